// Round 4
// baseline (579.165 us; speedup 1.0000x reference)
//
#include <hip/hip_runtime.h>

// Problem constants (match reference)
#define TB 8
#define TT 400
#define TS 40
#define TV 512
#define SU (TS + 1)          // 41
#define NROWS (TB * TT * SU) // 131200
#define KCH 16               // t-steps per chunk
#define NCH (TT / KCH)       // 25 chunks
#define RPC (TB * KCH * SU)  // rows per chunk           = 5248
#define RPBC (KCH * SU)      // rows per (batch, chunk)  = 656
#define NEG_INF (-1.0e30f)
#define INV_LN2 1.44269504088896341f
#define LN2 0.69314718055994531f

// VALU whole-wave shift-up-by-1 (DPP wave_shr:1); lane 0 sources 0 (harmless).
__device__ __forceinline__ float wave_shr1(float x) {
    return __int_as_float(
        __builtin_amdgcn_update_dpp(0, __float_as_int(x), 0x138, 0xf, 0xf, true));
}

// Fused producer/consumer kernel.
//  blockIdx < TB          : consumer — alpha recursion for batch b (1 wave)
//  blockIdx in [TB, ...)  : producer — per-row log-sum-exp, chunk-major order
// Sync: ctr[c*TB+b] counts completed rows of chunk c, batch b (target RPBC).
// Producers: agent-scope relaxed stores + vmcnt drain + relaxed agent add.
// Consumers: relaxed polls (prefetched one compute-phase early) + acquire fence.
__global__ __launch_bounds__(256) void fused_kernel(
    const float* __restrict__ acts, const int* __restrict__ labels,
    const int* __restrict__ input_lengths, const int* __restrict__ label_lengths,
    float* __restrict__ out,
    float* __restrict__ lp_blank, float* __restrict__ lp_label,
    unsigned int* ctr)
{
    if (blockIdx.x >= TB) {
        // ---------------- producer: row log-sum-exp ----------------
        const int wave = threadIdx.x >> 6;
        const int lane = threadIdx.x & 63;
        const int w = (blockIdx.x - TB) * 4 + wave;   // [0, NROWS)
        // chunk-major decode: (c, b, kt, u) — all batches progress together
        const int c  = w / RPC;
        const int r  = w - c * RPC;
        const int b  = r / RPBC;
        const int r2 = r - b * RPBC;
        const int kt = r2 / SU;
        const int u  = r2 - kt * SU;
        const int t  = c * KCH + kt;
        const int bt = b * TT + t;
        const int row = bt * SU + u;

        const float* rp = acts + (size_t)row * TV;
        float4 av = *(const float4*)(rp + lane * 8);
        float4 bv = *(const float4*)(rp + lane * 8 + 4);

        float m = fmaxf(fmaxf(fmaxf(av.x, av.y), fmaxf(av.z, av.w)),
                        fmaxf(fmaxf(bv.x, bv.y), fmaxf(bv.z, bv.w)));
#pragma unroll
        for (int off = 1; off < 64; off <<= 1) m = fmaxf(m, __shfl_xor(m, off));

        float s = __expf(av.x-m)+__expf(av.y-m)+__expf(av.z-m)+__expf(av.w-m)
                + __expf(bv.x-m)+__expf(bv.y-m)+__expf(bv.z-m)+__expf(bv.w-m);
#pragma unroll
        for (int off = 1; off < 64; off <<= 1) s += __shfl_xor(s, off);

        const float logZ = m + logf(s);

        if (lane == 0) {
            // agent-scope (device-coherent) stores, log2 domain
            __hip_atomic_store(&lp_blank[row], (av.x - logZ) * INV_LN2,
                               __ATOMIC_RELAXED, __HIP_MEMORY_SCOPE_AGENT);
            if (u < TS) {
                const int col = labels[b * TS + u];
                __hip_atomic_store(&lp_label[bt * TS + u],
                                   (rp[col] - logZ) * INV_LN2,
                                   __ATOMIC_RELAXED, __HIP_MEMORY_SCOPE_AGENT);
            }
            // ensure stores reached the coherence point before signaling
            asm volatile("s_waitcnt vmcnt(0)" ::: "memory");
            __hip_atomic_fetch_add(&ctr[c * TB + b], 1u,
                                   __ATOMIC_RELAXED, __HIP_MEMORY_SCOPE_AGENT);
        }
        return;
    }

    // ---------------- consumer: alpha recursion (1 wave) ----------------
    if (threadIdx.x >= 64) return;
    const int b = blockIdx.x;
    const int u = threadIdx.x;

    const int inlen  = input_lengths[b];
    const int lablen = label_lengths[b];
    const int c_sel  = (inlen - 1) / KCH;   // uniform: scalar select for 'saved'
    const int k_sel  = (inlen - 1) % KCH;

    const int uu = (u <= TS) ? u : TS;
    const int ul = (u >= 1 && u <= TS) ? (u - 1) : 0;
    const float* pb_ptr = lp_blank + (size_t)b * TT * SU + uu;
    const float* pl_ptr = lp_label + (size_t)b * TT * TS + ul;
    const bool u_dead = (u == 0 || u > TS);   // poison lp_label at load time

    float alpha = (u == 0) ? 0.0f : NEG_INF;
    float saved = NEG_INF;
    const unsigned int TGT = RPBC;

    float pbA[KCH], plA[KCH], pbB[KCH], plB[KCH];

#define PISSUE(C) __hip_atomic_load( \
        &ctr[(((C) < NCH ? (C) : (NCH - 1))) * TB + b], \
        __ATOMIC_RELAXED, __HIP_MEMORY_SCOPE_AGENT)

#define PWAIT(V, C) { unsigned int vv = (V); \
        while (vv < TGT) { __builtin_amdgcn_s_sleep(1); vv = PISSUE(C); } \
        __builtin_amdgcn_fence(__ATOMIC_ACQUIRE, "agent"); }

#define LOADC(PB, PL, C) { \
    _Pragma("unroll") \
    for (int k = 0; k < KCH; ++k) { \
        (PB)[k] = pb_ptr[((C) * KCH + k) * SU]; \
        float plv = pl_ptr[((C) * KCH + k) * TS]; \
        (PL)[k] = u_dead ? NEG_INF : plv; \
    } }

#define COMPUTE(PB, PL, C) { \
    _Pragma("unroll") \
    for (int k = 0; k < KCH; ++k) { \
        const float prev = wave_shr1(alpha); \
        const float stay = alpha + (PB)[k]; \
        const float move = prev + (PL)[k]; \
        const float mx = fmaxf(stay, move); \
        const float mn = fminf(stay, move); \
        alpha = mx + __builtin_amdgcn_logf(1.0f + __builtin_amdgcn_exp2f(mn - mx)); \
        if ((C) == c_sel && k == k_sel) saved = alpha; \
    } }

    { unsigned int v0 = PISSUE(0); PWAIT(v0, 0); }
    LOADC(pbA, plA, 0);
    unsigned int v1 = PISSUE(1);
    for (int i = 0; i < 12; ++i) {
        const int c0 = 2 * i;
        PWAIT(v1, c0 + 1);
        LOADC(pbB, plB, c0 + 1);
        unsigned int v2 = PISSUE(c0 + 2);
        COMPUTE(pbA, plA, c0);
        PWAIT(v2, c0 + 2);
        LOADC(pbA, plA, c0 + 2);
        v1 = PISSUE(c0 + 3);           // clamped to NCH-1 on last iter (unused)
        COMPUTE(pbB, plB, c0 + 1);
    }
    COMPUTE(pbA, plA, NCH - 1);

#undef PISSUE
#undef PWAIT
#undef LOADC
#undef COMPUTE

    const float cost_alpha = __shfl(saved, lablen);
    if (u == 0) out[b] = -cost_alpha * LN2;   // back to natural log
}

extern "C" void kernel_launch(void* const* d_in, const int* in_sizes, int n_in,
                              void* d_out, int out_size, void* d_ws, size_t ws_size,
                              hipStream_t stream) {
    const float* acts          = (const float*)d_in[0];
    const int*   labels        = (const int*)d_in[1];
    const int*   input_lengths = (const int*)d_in[2];
    const int*   label_lengths = (const int*)d_in[3];
    float* out = (float*)d_out;

    float* lp_blank = (float*)d_ws;                 // NROWS floats
    float* lp_label = lp_blank + NROWS;             // TB*TT*TS floats
    const size_t ctr_off = (size_t)NROWS * 4 + (size_t)TB * TT * TS * 4; // 1036800, 256B-aligned
    unsigned int* ctr = (unsigned int*)((char*)d_ws + ctr_off);          // NCH*TB entries

    hipMemsetAsync((void*)ctr, 0, NCH * TB * sizeof(unsigned int), stream);
    fused_kernel<<<TB + NROWS / 4, 256, 0, stream>>>(
        acts, labels, input_lengths, label_lengths, out,
        lp_blank, lp_label, ctr);
}

// Round 5
// 74.271 us; speedup vs baseline: 7.7980x; 7.7980x over previous
//
#include <hip/hip_runtime.h>

// Problem constants (match reference)
#define TB 8
#define TT 400
#define TS 40
#define TV 512
#define SU (TS + 1)          // 41
#define NROWS (TB * TT * SU) // 131200
#define KCH 16               // t-steps per chunk
#define NCH (TT / KCH)       // 25 chunks
#define RPC (TB * KCH * SU)  // rows per chunk           = 5248
#define RPBC (KCH * SU)      // rows per (batch, chunk)  = 656 = 4*164
#define BLKS_PER_BC (RPBC / 4)  // producer blocks per (c,b) = 164
#define CTR_STRIDE 32        // uints: 128B per counter line
#define NEG_INF (-1.0e30f)
#define INV_LN2 1.44269504088896341f
#define LN2 0.69314718055994531f

// VALU whole-wave shift-up-by-1 (DPP wave_shr:1); lane 0 sources 0 (harmless).
__device__ __forceinline__ float wave_shr1(float x) {
    return __int_as_float(
        __builtin_amdgcn_update_dpp(0, __float_as_int(x), 0x138, 0xf, 0xf, true));
}

// Fused producer/consumer kernel.
//  blockIdx < TB          : consumer — alpha recursion for batch b (1 wave)
//  blockIdx in [TB, ...)  : producer — per-row log-sum-exp, chunk-major order
// Sync: ctr[(b*NCH+c)*32] counts completed producer BLOCKS (4 rows each) of
// chunk c, batch b; target BLKS_PER_BC. One padded 128B line per counter;
// concurrently-updated counters (same c, different b) are ~3.2KB apart.
// Producers: sc1 stores + vmcnt drain + __syncthreads + ONE atomic per block.
// Consumers: relaxed polls (prefetched early) + acquire fence + sc1 data loads.
__global__ __launch_bounds__(256) void fused_kernel(
    const float* __restrict__ acts, const int* __restrict__ labels,
    const int* __restrict__ input_lengths, const int* __restrict__ label_lengths,
    float* __restrict__ out,
    float* __restrict__ lp_blank, float* __restrict__ lp_label,
    unsigned int* ctr)
{
    if (blockIdx.x >= TB) {
        // ---------------- producer: row log-sum-exp ----------------
        const int wave = threadIdx.x >> 6;
        const int lane = threadIdx.x & 63;
        const int w = (blockIdx.x - TB) * 4 + wave;   // [0, NROWS)
        // chunk-major decode: (c, b, kt, u) — all batches progress together
        const int c  = w / RPC;
        const int r  = w - c * RPC;
        const int b  = r / RPBC;
        const int r2 = r - b * RPBC;
        const int kt = r2 / SU;
        const int u  = r2 - kt * SU;
        const int t  = c * KCH + kt;
        const int bt = b * TT + t;
        const int row = bt * SU + u;

        const float* rp = acts + (size_t)row * TV;
        float4 av = *(const float4*)(rp + lane * 8);
        float4 bv = *(const float4*)(rp + lane * 8 + 4);

        float m = fmaxf(fmaxf(fmaxf(av.x, av.y), fmaxf(av.z, av.w)),
                        fmaxf(fmaxf(bv.x, bv.y), fmaxf(bv.z, bv.w)));
#pragma unroll
        for (int off = 1; off < 64; off <<= 1) m = fmaxf(m, __shfl_xor(m, off));

        float s = __expf(av.x-m)+__expf(av.y-m)+__expf(av.z-m)+__expf(av.w-m)
                + __expf(bv.x-m)+__expf(bv.y-m)+__expf(bv.z-m)+__expf(bv.w-m);
#pragma unroll
        for (int off = 1; off < 64; off <<= 1) s += __shfl_xor(s, off);

        const float logZ = m + logf(s);

        if (lane == 0) {
            // device-coherent stores (reach coherence point), log2 domain
            __hip_atomic_store(&lp_blank[row], (av.x - logZ) * INV_LN2,
                               __ATOMIC_RELAXED, __HIP_MEMORY_SCOPE_AGENT);
            if (u < TS) {
                const int col = labels[b * TS + u];
                __hip_atomic_store(&lp_label[bt * TS + u],
                                   (rp[col] - logZ) * INV_LN2,
                                   __ATOMIC_RELAXED, __HIP_MEMORY_SCOPE_AGENT);
            }
        }
        // drain this wave's stores to the coherence point, then block-barrier:
        // after the barrier all 4 waves' lp stores are globally visible.
        asm volatile("s_waitcnt vmcnt(0)" ::: "memory");
        __syncthreads();
        if (threadIdx.x == 0) {
            // one non-returning atomic per block (4 rows), padded counter line
            __hip_atomic_fetch_add(&ctr[(b * NCH + c) * CTR_STRIDE], 1u,
                                   __ATOMIC_RELAXED, __HIP_MEMORY_SCOPE_AGENT);
        }
        return;
    }

    // ---------------- consumer: alpha recursion (1 wave) ----------------
    if (threadIdx.x >= 64) return;
    const int b = blockIdx.x;
    const int u = threadIdx.x;

    const int inlen  = input_lengths[b];
    const int lablen = label_lengths[b];
    const int c_sel  = (inlen - 1) / KCH;   // uniform scalar select for 'saved'
    const int k_sel  = (inlen - 1) % KCH;

    const int uu = (u <= TS) ? u : TS;
    const int ul = (u >= 1 && u <= TS) ? (u - 1) : 0;
    const float* pb_ptr = lp_blank + (size_t)b * TT * SU + uu;
    const float* pl_ptr = lp_label + (size_t)b * TT * TS + ul;
    const bool u_dead = (u == 0 || u > TS);   // poison lp_label at load time

    float alpha = (u == 0) ? 0.0f : NEG_INF;
    float saved = NEG_INF;
    const unsigned int TGT = BLKS_PER_BC;

    float pbA[KCH], plA[KCH], pbB[KCH], plB[KCH];

#define PISSUE(C) __hip_atomic_load( \
        &ctr[(b * NCH + (((C) < NCH) ? (C) : (NCH - 1))) * CTR_STRIDE], \
        __ATOMIC_RELAXED, __HIP_MEMORY_SCOPE_AGENT)

#define PWAIT(V, C) { unsigned int vv = (V); \
        while (vv < TGT) { __builtin_amdgcn_s_sleep(1); vv = PISSUE(C); } \
        __builtin_amdgcn_fence(__ATOMIC_ACQUIRE, "agent"); }

// data loads bypass the (possibly stale) local L1/L2: agent-scope relaxed
#define LOADC(PB, PL, C) { \
    _Pragma("unroll") \
    for (int k = 0; k < KCH; ++k) { \
        (PB)[k] = __hip_atomic_load(&pb_ptr[((C) * KCH + k) * SU], \
                      __ATOMIC_RELAXED, __HIP_MEMORY_SCOPE_AGENT); \
        float plv = __hip_atomic_load(&pl_ptr[((C) * KCH + k) * TS], \
                      __ATOMIC_RELAXED, __HIP_MEMORY_SCOPE_AGENT); \
        (PL)[k] = u_dead ? NEG_INF : plv; \
    } }

#define COMPUTE(PB, PL, C) { \
    _Pragma("unroll") \
    for (int k = 0; k < KCH; ++k) { \
        const float prev = wave_shr1(alpha); \
        const float stay = alpha + (PB)[k]; \
        const float move = prev + (PL)[k]; \
        const float mx = fmaxf(stay, move); \
        const float mn = fminf(stay, move); \
        alpha = mx + __builtin_amdgcn_logf(1.0f + __builtin_amdgcn_exp2f(mn - mx)); \
        if ((C) == c_sel && k == k_sel) saved = alpha; \
    } }

    { unsigned int v0 = PISSUE(0); PWAIT(v0, 0); }
    LOADC(pbA, plA, 0);
    unsigned int v1 = PISSUE(1);
    for (int i = 0; i < 12; ++i) {
        const int c0 = 2 * i;
        PWAIT(v1, c0 + 1);
        LOADC(pbB, plB, c0 + 1);
        unsigned int v2 = PISSUE(c0 + 2);
        COMPUTE(pbA, plA, c0);
        PWAIT(v2, c0 + 2);
        LOADC(pbA, plA, c0 + 2);
        v1 = PISSUE(c0 + 3);           // clamped to NCH-1 on last iter (unused)
        COMPUTE(pbB, plB, c0 + 1);
    }
    COMPUTE(pbA, plA, NCH - 1);

#undef PISSUE
#undef PWAIT
#undef LOADC
#undef COMPUTE

    const float cost_alpha = __shfl(saved, lablen);
    if (u == 0) out[b] = -cost_alpha * LN2;   // back to natural log
}

extern "C" void kernel_launch(void* const* d_in, const int* in_sizes, int n_in,
                              void* d_out, int out_size, void* d_ws, size_t ws_size,
                              hipStream_t stream) {
    const float* acts          = (const float*)d_in[0];
    const int*   labels        = (const int*)d_in[1];
    const int*   input_lengths = (const int*)d_in[2];
    const int*   label_lengths = (const int*)d_in[3];
    float* out = (float*)d_out;

    float* lp_blank = (float*)d_ws;                 // NROWS floats
    float* lp_label = lp_blank + NROWS;             // TB*TT*TS floats
    const size_t ctr_off = (size_t)NROWS * 4 + (size_t)TB * TT * TS * 4; // 1036800, 256B-aligned
    unsigned int* ctr = (unsigned int*)((char*)d_ws + ctr_off);          // TB*NCH padded lines

    hipMemsetAsync((void*)ctr, 0, TB * NCH * CTR_STRIDE * sizeof(unsigned int), stream);
    fused_kernel<<<TB + NROWS / 4, 256, 0, stream>>>(
        acts, labels, input_lengths, label_lengths, out,
        lp_blank, lp_label, ctr);
}